// Round 8
// baseline (261.997 us; speedup 1.0000x reference)
//
#include <hip/hip_runtime.h>

typedef unsigned short u16;
typedef unsigned char u8;
typedef signed char i8;
typedef int i32x4 __attribute__((ext_vector_type(4)));
typedef int i32x16 __attribute__((ext_vector_type(16)));
typedef float f32x4 __attribute__((ext_vector_type(4)));
typedef unsigned u32x4 __attribute__((ext_vector_type(4)));
typedef u8 u8x16 __attribute__((ext_vector_type(16)));

// Chunked spike layout: buf[ch][m][64], ch = d>>6 (6 chunks), m = (b*256+n)*4+t (32768 rows).
// CHS = 32768*64 bytes. Weights: W[lvl][ck][d][64], lvl stride 147456, ck stride 24576.
#define CHS 2097152L

// async global->LDS, 16B per lane (global_load_lds_dwordx4)
__device__ __forceinline__ void gload16(const void* g, void* l) {
    __builtin_amdgcn_global_load_lds(
        (const __attribute__((address_space(1))) void*)g,
        (__attribute__((address_space(3))) void*)l, 16, 0, 0);
}

// ---------- PREP: fused [k1: shortcut LIF + transpose -> u8 chunked] + [i8 weight levels chunked] ----------
// grid: 768 k1-blocks (3 c-tiles x 8 n-tiles x 32 b) + 384 weight blocks (1 row/wave); block 256
__global__ __launch_bounds__(256) void prep(const float* __restrict__ X, u8* __restrict__ Xt,
    const float* __restrict__ qw, const float* __restrict__ kw,
    const float* __restrict__ vw, const float* __restrict__ pw,
    i8* __restrict__ Wq, float* __restrict__ Sc, float* __restrict__ KVraw) {
    const int bid = blockIdx.x;
    if (bid < 768) {
        // LDS [t][n][c] u8 so the transpose READ is one 16B vector load
        __shared__ __attribute__((aligned(16))) u8 s2[4][32][136];
        const int c0 = (bid % 3) * 128;
        const int n0 = ((bid / 3) & 7) * 32;
        const int b = bid / 24;
        // f32x4 loads: lane handles 4 consecutive n (G13 vectorization)
        const int n4 = (threadIdx.x & 7) << 2;       // 0..28
        const int cl0 = threadIdx.x >> 3;            // 0..31
        #pragma unroll
        for (int pass = 0; pass < 4; pass++) {
            const int c_l = cl0 + (pass << 5);
            f32x4 vm = {0.f, 0.f, 0.f, 0.f};
            #pragma unroll
            for (int t = 0; t < 4; t++) {
                f32x4 xv = __builtin_nontemporal_load(
                    (const f32x4*)&X[(((long)t * 32 + b) * 384 + c0 + c_l) * 256 + n0 + n4]);
                #pragma unroll
                for (int e = 0; e < 4; e++) {
                    vm[e] += (xv[e] - vm[e]) * 0.5f;
                    u8 sp = 0;
                    if (vm[e] >= 1.0f) { sp = 1; vm[e] = 0.f; }
                    s2[t][n4 + e][c_l] = sp;
                }
            }
        }
        __syncthreads();
        const int c16 = (threadIdx.x & 7) << 4;       // 8 lanes x 16B = 128 c
        const int n = (threadIdx.x >> 3) & 31;
        const int cglob = c0 + c16;
        const int ch = cglob >> 6, off = cglob & 63;
        #pragma unroll
        for (int t = 0; t < 4; t++) {
            u8x16 v = *(const u8x16*)&s2[t][n][c16];
            *(u8x16*)&Xt[(long)ch * CHS + ((long)(b * 256 + n0 + n) * 4 + t) * 64 + off] = v;
        }
    } else {
        // i8 3-level (qkv) / 2-level (proj) quantization, one 384-wide row per wave, chunked output
        const int wv = bid - 768;                     // 0..383
        const int w = threadIdx.x >> 6, lane = threadIdx.x & 63;
        const int r = wv * 4 + w;                     // 0..1535
        const int m = r / 384, d = r - m * 384;
        const float* srcs[4] = {qw, kw, vw, pw};
        const float* row = srcs[m] + (long)d * 384;
        float a[6]; float mx = 0.f;
        #pragma unroll
        for (int jj = 0; jj < 6; jj++) { a[jj] = row[lane + (jj << 6)]; mx = fmaxf(mx, fabsf(a[jj])); }
        #pragma unroll
        for (int off = 1; off < 64; off <<= 1) mx = fmaxf(mx, __shfl_xor(mx, off));
        float scale = mx * (1.f / 127.f);
        float sinv = mx > 0.f ? 127.f / mx : 0.f;
        if (lane == 0) Sc[r] = scale;
        i8* dstb = Wq + (long)(m == 3 ? 9 : m * 3) * 147456 + (long)d * 64;
        #pragma unroll
        for (int jj = 0; jj < 6; jj++) {
            float x = a[jj] * sinv;
            float q1 = rintf(x);         float r1 = x - q1;
            float q2 = rintf(r1 * 128.f); float r2 = r1 * 128.f - q2;
            float q3 = rintf(r2 * 128.f);
            int co = jj * 24576 + lane;
            dstb[co] = (i8)(int)q1;
            dstb[147456 + co] = (i8)(int)q2;
            if (m != 3) dstb[2 * 147456 + co] = (i8)(int)q3;
        }
        const int idx = wv * 256 + threadIdx.x;
        if (idx < 49152) KVraw[idx] = 0.f;
    }
}

// ---------- i8 multi-level GEMM: 128x64 tile, BK=64, mfma_i32_32x32x32_i8 ----------
// T4 counted-vmcnt ping-pong: issue STAGE(ck+1), then s_waitcnt vmcnt(NL+2) retires ONLY the
// oldest 5 loads (tile ck) - the prefetch stays in flight across the barrier (m135/m218 pattern).
// Two raw s_barriers per tile: pre-compute (tile-ck data visible to all waves) and post-compute
// (no wave issues writes into the buffer others still read). sched_barrier(0) pins the compute
// phase below the waits (rule #18). Per-buffer: A [128][64] at +0, B level p at +8192 + p*4096.
// Dest byte = tid*16 (wave-linear). Swizzle: LDS 16B-slot s of row r holds global slot
// s ^ ((r>>1)&3); fragment reads apply the same XOR. cs(rA)==cs(rA+64).
template<int NL>
__device__ __forceinline__ void gemm_i8(const u8* __restrict__ A, const i8* __restrict__ B,
                                        char* lds8, int m0, int n0, i32x16 (&acc)[NL][2]) {
    const int tid = threadIdx.x, l = tid & 63, w = tid >> 6;
    const int wm = (w & 1) << 6, wn = (w >> 1) << 5;
    const int col = l & 31, kg = l >> 5;
    const int rA = tid >> 2, sl = tid & 3;
    const int cs = (sl ^ ((rA >> 1) & 3)) << 4;
    const u8* Ap = A + (long)(m0 + rA) * 64 + cs;
    const i8* Bp = B + (long)(n0 + rA) * 64 + cs;
    const int BUFSZ = (2 + NL) * 4096;
    char* dst = lds8 + tid * 16;

    // prologue: stage tile 0 into buffer 0 (no drain - iter 0's counted wait handles it)
    gload16(Ap, dst);
    gload16(Ap + 4096, dst + 4096);
    #pragma unroll
    for (int p = 0; p < NL; p++)
        gload16(Bp + p * 147456, dst + 8192 + p * 4096);

    for (int ck = 0; ck < 6; ck++) {
        const int cur = ck & 1;
        if (ck < 5) {   // prefetch next tile into the other buffer (stays in flight past barrier)
            char* d = dst + (cur ^ 1) * BUFSZ;
            gload16(Ap + (ck + 1) * CHS, d);
            gload16(Ap + (ck + 1) * CHS + 4096, d + 4096);
            #pragma unroll
            for (int p = 0; p < NL; p++)
                gload16(Bp + p * 147456 + (ck + 1) * 24576, d + 8192 + p * 4096);
            if (NL == 3) asm volatile("s_waitcnt vmcnt(5)" ::: "memory");
            else         asm volatile("s_waitcnt vmcnt(4)" ::: "memory");
        } else {
            asm volatile("s_waitcnt vmcnt(0)" ::: "memory");
        }
        __builtin_amdgcn_s_barrier();          // all waves' tile-ck data in LDS
        __builtin_amdgcn_sched_barrier(0);     // pin compute below the wait/barrier
        char* base = lds8 + cur * BUFSZ;
        #pragma unroll
        for (int c = 0; c < 2; c++) {
            i32x4 af[2];
            #pragma unroll
            for (int i = 0; i < 2; i++) {
                int ra = wm + (i << 5) + col;
                int sa = ((2 * c + kg) ^ ((ra >> 1) & 3)) << 4;
                af[i] = *(const i32x4*)(base + ra * 64 + sa);
            }
            int rb = wn + col;
            int sb = ((2 * c + kg) ^ ((rb >> 1) & 3)) << 4;
            #pragma unroll
            for (int p = 0; p < NL; p++) {
                i32x4 bf = *(const i32x4*)(base + 8192 + p * 4096 + rb * 64 + sb);
                #pragma unroll
                for (int i = 0; i < 2; i++)
                    acc[p][i] = __builtin_amdgcn_mfma_i32_32x32x32_i8(af[i], bf, acc[p][i], 0, 0, 0);
            }
        }
        __builtin_amdgcn_sched_barrier(0);     // keep compute above the release barrier
        __builtin_amdgcn_s_barrier();          // all reads of this buffer done before next overwrite
    }
}

// ---------- K2: q/k/v conv1x1 (3-level i8 GEMM) + scale + BN + LIF -> u8 spikes (chunked) ----------
// grid 4608: per m-tile, 18 subs (6 d-tiles x 3 branches) grouped on one XCD -> A-tile L2-resident.
__global__ __launch_bounds__(256, 4) void k2(
    const u8* __restrict__ Xt, const i8* __restrict__ Wq, const float* __restrict__ Sc,
    const float* __restrict__ g0, const float* __restrict__ b0, const float* __restrict__ m0_, const float* __restrict__ v0_,
    const float* __restrict__ g1, const float* __restrict__ b1, const float* __restrict__ m1_, const float* __restrict__ v1_,
    const float* __restrict__ g2, const float* __restrict__ b2, const float* __restrict__ m2_, const float* __restrict__ v2_,
    u8* __restrict__ oq, u8* __restrict__ ok, u8* __restrict__ ov, float* __restrict__ out1)
{
    __shared__ __attribute__((aligned(16))) char lds8[40960];   // 2 x 20KB staging; epilogue tile 128x80 u8 aliased
    const int bid = blockIdx.x;
    const int xcd = bid & 7, bi = bid >> 3;
    const int mt = (bi / 18) * 8 + xcd;
    const int sub = bi % 18;
    const int m0 = mt * 128, d0 = (sub % 6) * 64, br = sub / 6;
    const float* G  = br == 0 ? g0  : (br == 1 ? g1  : g2);
    const float* Be = br == 0 ? b0  : (br == 1 ? b1  : b2);
    const float* Mu = br == 0 ? m0_ : (br == 1 ? m1_ : m2_);
    const float* Va = br == 0 ? v0_ : (br == 1 ? v1_ : v2_);

    i32x16 acc[3][2];
    #pragma unroll
    for (int p = 0; p < 3; p++)
        #pragma unroll
        for (int i = 0; i < 2; i++)
            #pragma unroll
            for (int r = 0; r < 16; r++) acc[p][i][r] = 0;
    gemm_i8<3>(Xt, Wq + (long)br * 3 * 147456, lds8, m0, d0, acc);

    const int tid = threadIdx.x, l = tid & 63, w = tid >> 6;
    const int wm = (w & 1) << 6, wn = (w >> 1) << 5;
    const int col = l & 31;
    const int d = d0 + wn + col;
    const float scb = G[d] / sqrtf(Va[d] + 1e-5f);
    const float mu = Mu[d], be = Be[d];
    const float wsc = Sc[br * 384 + d];
    u8* tile8 = (u8*)lds8;   // stride 80
    const float c1 = 0.0078125f, c2 = 6.103515625e-05f;
    #pragma unroll
    for (int i = 0; i < 2; i++)
        #pragma unroll
        for (int q = 0; q < 4; q++) {
            float vm = 0.f;
            int mb = wm + (i << 5) + (q << 3) + ((l >> 5) << 2);
            #pragma unroll
            for (int t = 0; t < 4; t++) {
                int reg = q * 4 + t;
                float f = (float)acc[0][i][reg] + (float)acc[1][i][reg] * c1
                        + (float)acc[2][i][reg] * c2;
                float bn = (f * wsc - mu) * scb + be;
                vm += (bn - vm) * 0.5f;
                u8 s = 0;
                if (vm >= 1.0f) { s = 1; vm = 0.f; }
                tile8[(mb + t) * 80 + wn + col] = s;
            }
        }
    __syncthreads();
    // Out8 chunked: dense 8KB region, per-instruction-contiguous (lane l -> byte l*16). Cached
    // (no NT): k3a/k4 consume these next launch.
    u8* Out8 = br == 0 ? oq : (br == 1 ? ok : ov);
    const long rbase = (long)(d0 >> 6) * CHS + (long)m0 * 64;
    u32x4 w0 = *(const u32x4*)&tile8[(tid >> 2) * 80 + ((tid & 3) << 4)];
    u32x4 w1 = *(const u32x4*)&tile8[(64 + (tid >> 2)) * 80 + ((tid & 3) << 4)];
    *(u32x4*)(Out8 + rbase + tid * 16) = w0;
    *(u32x4*)(Out8 + rbase + 4096 + tid * 16) = w1;
    if (br == 2) {   // output 1: v spikes as f32 in (T,B,h,N,Ch); final output -> NT, full lines
        const int b = m0 >> 10, n_base = (m0 >> 2) & 255;
        const int dl4 = (tid & 15) << 2;
        const int d2 = d0 + dl4;
        const int h = d2 / 48, chn = d2 - h * 48;
        #pragma unroll
        for (int q = 0; q < 8; q++) {
            int mlq = (tid >> 4) + (q << 4);
            int t = mlq & 3, n = n_base + (mlq >> 2);
            f32x4 v;
            #pragma unroll
            for (int r = 0; r < 4; r++) v[r] = tile8[mlq * 80 + dl4 + r] ? 1.0f : 0.f;
            long gi = ((((long)t * 32 + b) * 8 + h) * 256 + n) * 48 + chn;
            __builtin_nontemporal_store(v, (f32x4*)&out1[gi]);
        }
    }
}

// ---------- K3a: kv partial counts (exact int), uchar4 loads, chunked ----------
__global__ __launch_bounds__(384) void k3a(const u8* __restrict__ Ks, const u8* __restrict__ Vs,
                                           float* __restrict__ kv_raw) {
    const int b = blockIdx.y, nc = blockIdx.x;
    const int d4 = threadIdx.x * 4, t = threadIdx.y;
    const long cbase = (long)(d4 >> 6) * CHS + (d4 & 63);
    int cnt0 = 0, cnt1 = 0, cnt2 = 0, cnt3 = 0;
    for (int nl = 0; nl < 32; nl++) {
        const long row = ((long)b * 256 + nc * 32 + nl) * 4 + t;
        uchar4 kk = *(const uchar4*)&Ks[cbase + row * 64];
        uchar4 vv = *(const uchar4*)&Vs[cbase + row * 64];
        cnt0 += (kk.x & vv.x); cnt1 += (kk.y & vv.y);
        cnt2 += (kk.z & vv.z); cnt3 += (kk.w & vv.w);
    }
    float* dst = &kv_raw[((long)t * 32 + b) * 384 + d4];
    atomicAdd(dst + 0, (float)cnt0);
    atomicAdd(dst + 1, (float)cnt1);
    atomicAdd(dst + 2, (float)cnt2);
    atomicAdd(dst + 3, (float)cnt3);
}

// ---------- K4: [k3b LIF mask + k3c AND fused] proj GEMM (2-level i8) + bias + BN + identity -> f32 ----------
// grid 1536: per m-tile, 6 e-tiles grouped on one XCD. A = (Qs & kvs-mask) reg-staged with T14
// write-late: issue loads -> compute (covers latency) -> ds_write -> barrier. B via gload_lds.
__global__ __launch_bounds__(256, 4) void k4(
    const u8* __restrict__ Qs, const float* __restrict__ kv_raw,
    const i8* __restrict__ Pq, const float* __restrict__ Scp,
    const float* __restrict__ PB, const float* __restrict__ PG, const float* __restrict__ PBe,
    const float* __restrict__ PM, const float* __restrict__ PV,
    const float* __restrict__ X, float* __restrict__ O)
{
    // [0,32768): 2 x 16KB staging dbuf; [0,33792): f32 epilogue tile [64][132] (aliases staging);
    // [33792,35328): kvs mask u8[4][384] (persistent).
    __shared__ __attribute__((aligned(16))) char lds8[35328];
    u8* kvs_s = (u8*)(lds8 + 33792);
    const int bid = blockIdx.x;
    const int xcd = bid & 7, bi = bid >> 3;
    const int mt = (bi / 6) * 8 + xcd;
    const int m0 = mt * 128, e0 = (bi % 6) * 64;
    const int tid = threadIdx.x;
    const int b = m0 >> 10;

    // ---- mask prologue: LIF(kv_raw, v_th=0.5) for this b ----
    for (int dd = tid; dd < 384; dd += 256) {
        float vm = 0.f;
        #pragma unroll
        for (int t = 0; t < 4; t++) {
            vm += (kv_raw[((long)t * 32 + b) * 384 + dd] - vm) * 0.5f;
            u8 sp = 0;
            if (vm >= 0.5f) { sp = 1; vm = 0.f; }
            kvs_s[t * 384 + dd] = sp;
        }
    }
    __syncthreads();

    // ---- GEMM: reg-staged A (= Qs & mask) write-late, gload_lds B, ping-pong ----
    i32x16 acc[2][2];
    #pragma unroll
    for (int p = 0; p < 2; p++)
        #pragma unroll
        for (int i = 0; i < 2; i++)
            #pragma unroll
            for (int r = 0; r < 16; r++) acc[p][i][r] = 0;
    const int l = tid & 63, w = tid >> 6;
    const int wm = (w & 1) << 6, wn = (w >> 1) << 5;
    const int col = l & 31, kg = l >> 5;
    const int rA = tid >> 2, sl = tid & 3;
    const int cs = (sl ^ ((rA >> 1) & 3)) << 4;
    const int tA = rA & 3;                        // t of both staged rows (rA and rA+64)
    const u8* Ap = Qs + (long)(m0 + rA) * 64 + cs;
    const i8* Bp = Pq + (long)(e0 + rA) * 64 + cs;
    const int BUFSZ = 16384;
    char* dst = lds8 + tid * 16;
    {   // stage tile 0 into buffer 0 (one-time cold stall is fine)
        u32x4 mk = *(const u32x4*)&kvs_s[tA * 384 + cs];
        u32x4 q0 = *(const u32x4*)(Ap);
        u32x4 q1 = *(const u32x4*)(Ap + 4096);
        gload16(Bp, dst + 8192);
        gload16(Bp + 147456, dst + 12288);
        *(u32x4*)dst = q0 & mk;
        *(u32x4*)(dst + 4096) = q1 & mk;
    }
    __syncthreads();
    for (int ck = 0; ck < 6; ck++) {
        const int cur = ck & 1;
        u32x4 qn0, qn1, mk;
        char* dn = dst + (cur ^ 1) * BUFSZ;
        if (ck < 5) {   // T14 issue-early: loads + B gloads in flight during compute
            mk = *(const u32x4*)&kvs_s[tA * 384 + (ck + 1) * 64 + cs];
            qn0 = *(const u32x4*)(Ap + (ck + 1) * CHS);
            qn1 = *(const u32x4*)(Ap + (ck + 1) * CHS + 4096);
            gload16(Bp + (ck + 1) * 24576, dn + 8192);
            gload16(Bp + 147456 + (ck + 1) * 24576, dn + 12288);
        }
        char* base = lds8 + cur * BUFSZ;
        #pragma unroll
        for (int c = 0; c < 2; c++) {
            i32x4 af[2];
            #pragma unroll
            for (int i = 0; i < 2; i++) {
                int ra = wm + (i << 5) + col;
                int sa = ((2 * c + kg) ^ ((ra >> 1) & 3)) << 4;
                af[i] = *(const i32x4*)(base + ra * 64 + sa);
            }
            int rb = wn + col;
            int sb = ((2 * c + kg) ^ ((rb >> 1) & 3)) << 4;
            #pragma unroll
            for (int p = 0; p < 2; p++) {
                i32x4 bf = *(const i32x4*)(base + 8192 + p * 4096 + rb * 64 + sb);
                #pragma unroll
                for (int i = 0; i < 2; i++)
                    acc[p][i] = __builtin_amdgcn_mfma_i32_32x32x32_i8(af[i], bf, acc[p][i], 0, 0, 0);
            }
        }
        if (ck < 5) {   // T14 write-late: loads have had the whole MFMA phase to land
            *(u32x4*)dn = qn0 & mk;
            *(u32x4*)(dn + 4096) = qn1 & mk;
        }
        __syncthreads();   // drains B gloads (covered by compute) + releases buffer
    }

    // ---- epilogue: scale + bias + BN, transpose via LDS, identity add, NT out ----
    const int e = e0 + wn + col;
    const float scb = PG[e] / sqrtf(PV[e] + 1e-5f);
    const float mu = PM[e], be = PBe[e], pbb = PB[e];
    const float wsc = Scp[e];
    float* smemf = (float*)lds8;   // [e 64][m 132] transposed: b128 reads + coalesced stores
    const float c1 = 0.0078125f;
    #pragma unroll
    for (int i = 0; i < 2; i++)
        #pragma unroll
        for (int q = 0; q < 4; q++)
            #pragma unroll
            for (int t = 0; t < 4; t++) {
                int reg = q * 4 + t;
                float f = (float)acc[0][i][reg] + (float)acc[1][i][reg] * c1;
                float z = (f * wsc + pbb - mu) * scb + be;
                int m = wm + (i << 5) + (q << 3) + ((l >> 5) << 2) + t;
                smemf[(wn + col) * 132 + m] = z;
            }
    __syncthreads();
    const int n_base = (m0 >> 2) & 255;
    const int n_l = tid & 31;
    #pragma unroll
    for (int ei = 0; ei < 8; ei++) {
        int e_l = (tid >> 5) + (ei << 3);
        f32x4 v = *(const f32x4*)&smemf[e_l * 132 + (n_l << 2)];
        #pragma unroll
        for (int t = 0; t < 4; t++) {
            long gi = (((long)t * 32 + b) * 384 + e0 + e_l) * 256 + n_base + n_l;
            float xv = __builtin_nontemporal_load(&X[gi]);
            __builtin_nontemporal_store(v[t] + xv, &O[gi]);
        }
    }
}

extern "C" void kernel_launch(void* const* d_in, const int* in_sizes, int n_in,
                              void* d_out, int out_size, void* d_ws, size_t ws_size,
                              hipStream_t stream) {
    (void)in_sizes; (void)n_in; (void)out_size; (void)ws_size;
    const float* x   = (const float*)d_in[0];
    const float* qw  = (const float*)d_in[1];
    const float* qg  = (const float*)d_in[2];
    const float* qb  = (const float*)d_in[3];
    const float* qm  = (const float*)d_in[4];
    const float* qv  = (const float*)d_in[5];
    const float* kw  = (const float*)d_in[6];
    const float* kg  = (const float*)d_in[7];
    const float* kb  = (const float*)d_in[8];
    const float* km  = (const float*)d_in[9];
    const float* kv  = (const float*)d_in[10];
    const float* vw  = (const float*)d_in[11];
    const float* vg  = (const float*)d_in[12];
    const float* vb  = (const float*)d_in[13];
    const float* vm  = (const float*)d_in[14];
    const float* vv  = (const float*)d_in[15];
    const float* pw  = (const float*)d_in[16];
    const float* pb  = (const float*)d_in[17];
    const float* pg  = (const float*)d_in[18];
    const float* pbe = (const float*)d_in[19];
    const float* pm  = (const float*)d_in[20];
    const float* pv  = (const float*)d_in[21];

    // out0 (50.3 MB) as scratch until k4 writes it:
    //   Qs8 u8 @ [0, 12582912)           (read by k4 directly; dead after k4)
    //   Xt8 u8 @ [12582912, 25165824)    (dead after k2)
    // ws: Ks8/Vs8 u8, KVraw, Wq i8 (11 levels), Sc f32
    float* out0 = (float*)d_out;
    float* out1 = out0 + 12582912;
    char*  ob   = (char*)d_out;
    u8*    Qs8  = (u8*)ob;
    u8*    Xt8  = (u8*)(ob + 12582912);
    char*  ws   = (char*)d_ws;
    u8*    Ks8  = (u8*)ws;
    u8*    Vs8  = (u8*)ws + 12582912;
    float* KVraw = (float*)(ws + 25165824);      // 196608 B
    i8*    Wq    = (i8*)(ws + 25411584);         // 11*147456 = 1622016 B
    float* Sc    = (float*)(ws + 27033600);      // 1536*4 = 6144 B

    hipLaunchKernelGGL(prep, dim3(1152), dim3(256), 0, stream, x, Xt8, qw, kw, vw, pw, Wq, Sc, KVraw);
    hipLaunchKernelGGL(k2, dim3(4608), dim3(256), 0, stream,
                       Xt8, Wq, Sc,
                       qg, qb, qm, qv,
                       kg, kb, km, kv,
                       vg, vb, vm, vv,
                       Qs8, Ks8, Vs8, out1);
    hipLaunchKernelGGL(k3a, dim3(8, 32), dim3(96, 4), 0, stream, Ks8, Vs8, KVraw);
    hipLaunchKernelGGL(k4, dim3(1536), dim3(256), 0, stream,
                       Qs8, KVraw, Wq + 9 * 147456L, Sc + 3 * 384, pb, pg, pbe, pm, pv, x, out0);
}